// Round 1
// baseline (354.611 us; speedup 1.0000x reference)
//
#include <hip/hip_runtime.h>
#include <hip/hip_bf16.h>

// ---------------------------------------------------------------------------
// Model: GCN chain -> fcg  ||  conv1 -> conv2 -> fcc  -> concat -> MLP head
// B=64, K(nodes)=128, N_BAND=5, HW=128, CH=16
// ---------------------------------------------------------------------------

#define NROWS   8192      // B*K
#define IMG     16384     // 128*128
#define FCC_K   262144    // 16*128*128
#define FCC_BLOCKS 512
#define FCC_KRANGE 512    // FCC_K / FCC_BLOCKS
#define FCC_KS  64        // LDS sub-chunk

// ---------------------------------------------------------------------------
// Kernel 1: full GCN chain + fcg, single block (1024 threads).
// h1 (8192x10) staged in global ws; h2 (8192) staged in LDS.
// ---------------------------------------------------------------------------
__global__ __launch_bounds__(1024) void gcn_kernel(
    const float* __restrict__ x1,    // (8192,5)
    const float* __restrict__ W1,    // (5,10)
    const float* __restrict__ b1,    // (10)
    const float* __restrict__ W2,    // (10,1)
    const float* __restrict__ b2,    // (1)
    const float* __restrict__ fcgW,  // (128,128)
    const float* __restrict__ fcgb,  // (128)
    float* __restrict__ h1,          // ws: 8192*10
    float* __restrict__ g)           // ws: 64*128
{
    __shared__ float sW1[50], sb1[10], sW2[10], smean[10];
    __shared__ float sh2[NROWS];     // 32 KB
    int tid = threadIdx.x;
    if (tid < 50) sW1[tid] = W1[tid];
    if (tid < 10) { sb1[tid] = b1[tid]; sW2[tid] = W2[tid]; }
    __syncthreads();

    // phase 1: y1 = x1@W1 ; rows>=128 get bias+relu now, rows<128 stay raw
    for (int r = tid; r < NROWS; r += 1024) {
        float x[5];
        #pragma unroll
        for (int f = 0; f < 5; ++f) x[f] = x1[r*5 + f];
        #pragma unroll
        for (int o = 0; o < 10; ++o) {
            float y = 0.f;
            #pragma unroll
            for (int f = 0; f < 5; ++f) y += x[f] * sW1[f*10 + o];
            if (r >= 128) y = fmaxf(y + sb1[o], 0.f);
            h1[r*10 + o] = y;
        }
    }
    __syncthreads();

    // phase 2: column means of raw rows 0..127, then bias+relu
    if (tid < 10) {
        float s = 0.f;
        for (int r = 0; r < 128; ++r) s += h1[r*10 + tid];
        smean[tid] = fmaxf(s * (1.f/128.f) + sb1[tid], 0.f);
    }
    __syncthreads();

    // phase 3: broadcast mean value into rows 0..127
    for (int idx = tid; idx < 128*10; idx += 1024)
        h1[idx] = smean[idx % 10];
    __syncthreads();

    // phase 4: y2 = h1@W2 (10->1); same mean trick
    for (int r = tid; r < NROWS; r += 1024) {
        float y = 0.f;
        #pragma unroll
        for (int f = 0; f < 10; ++f) y += h1[r*10 + f] * sW2[f];
        if (r >= 128) y = fmaxf(y + b2[0], 0.f);
        sh2[r] = y;
    }
    __syncthreads();

    // phase 5: mean of sh2[0..127]
    if (tid == 0) {
        float s = 0.f;
        for (int r = 0; r < 128; ++r) s += sh2[r];
        float v = fmaxf(s * (1.f/128.f) + b2[0], 0.f);
        for (int r = 0; r < 128; ++r) sh2[r] = v;
    }
    __syncthreads();

    // phase 6: g = relu(h2 @ fcgW + fcgb)   (64x128)@(128x128)
    for (int o = tid; o < 64*128; o += 1024) {
        int b = o >> 7, n = o & 127;
        float acc = fcgb[n];
        const float* h2row = &sh2[b*128];
        for (int k = 0; k < 128; ++k) acc += h2row[k] * fcgW[k*128 + n];
        g[o] = fmaxf(acc, 0.f);
    }
}

// ---------------------------------------------------------------------------
// Kernel 2: conv1 (1 -> 16 ch, 3x3 SAME, relu). Thread per pixel.
// ---------------------------------------------------------------------------
__global__ __launch_bounds__(256) void conv1_kernel(
    const float* __restrict__ x2,    // (64,128,128)
    const float* __restrict__ w,     // (16,1,3,3)
    const float* __restrict__ bias,  // (16)
    float* __restrict__ c1)          // (64,16,128,128)
{
    __shared__ float sw[144], sb[16];
    int tid = threadIdx.x;
    if (tid < 144) sw[tid] = w[tid];
    if (tid < 16)  sb[tid] = bias[tid];
    __syncthreads();

    int gidx = blockIdx.x * 256 + tid;      // 0 .. 64*16384
    int b = gidx >> 14;
    int p = gidx & (IMG - 1);
    int i = p >> 7, j = p & 127;
    const float* xb = x2 + b * IMG;

    float in[3][3];
    #pragma unroll
    for (int di = 0; di < 3; ++di)
      #pragma unroll
      for (int dj = 0; dj < 3; ++dj) {
          int ii = i + di - 1, jj = j + dj - 1;
          in[di][dj] = (ii >= 0 && ii < 128 && jj >= 0 && jj < 128)
                       ? xb[ii*128 + jj] : 0.f;
      }

    #pragma unroll
    for (int oc = 0; oc < 16; ++oc) {
        float acc = sb[oc];
        #pragma unroll
        for (int di = 0; di < 3; ++di)
          #pragma unroll
          for (int dj = 0; dj < 3; ++dj)
              acc += in[di][dj] * sw[oc*9 + di*3 + dj];
        c1[(b*16 + oc)*IMG + p] = fmaxf(acc, 0.f);
    }
}

// ---------------------------------------------------------------------------
// Kernel 3: conv2 (16 -> 16 ch, 3x3 SAME, relu). 32x32 tile + halo in LDS.
// ---------------------------------------------------------------------------
__global__ __launch_bounds__(256) void conv2_kernel(
    const float* __restrict__ c1,    // (64,16,128,128)
    const float* __restrict__ w,     // (16,16,3,3)
    const float* __restrict__ bias,  // (16)
    float* __restrict__ c2)          // (64,16,128,128)
{
    __shared__ float sin[16][34][34];   // ~74 KB
    __shared__ float sw[144][16];       // [ic*9+di*3+dj][oc]
    __shared__ float sb[16];
    int tid = threadIdx.x;
    int blk = blockIdx.x;               // 64 images * 16 tiles
    int b   = blk >> 4;
    int tile = blk & 15;
    int i0 = (tile >> 2) * 32, j0 = (tile & 3) * 32;

    // weights: w[oc][ic][di][dj] flat = oc*144 + rest
    for (int idx = tid; idx < 2304; idx += 256) {
        int oc = idx & 15, rest = idx >> 4;
        sw[rest][oc] = w[oc*144 + rest];
    }
    if (tid < 16) sb[tid] = bias[tid];

    const float* cb = c1 + b * 16 * IMG;
    for (int idx = tid; idx < 16*34*34; idx += 256) {
        int ic  = idx / 1156;
        int rem = idx - ic*1156;
        int r = rem / 34, cc = rem - r*34;
        int gi = i0 + r - 1, gj = j0 + cc - 1;
        float v = 0.f;
        if (gi >= 0 && gi < 128 && gj >= 0 && gj < 128)
            v = cb[ic*IMG + gi*128 + gj];
        sin[ic][r][cc] = v;
    }
    __syncthreads();

    int cq = tid & 31;      // column within tile
    int r0 = tid >> 5;      // row group 0..7 (handles rows r0, r0+8, r0+16, r0+24)
    float acc[4][16];
    #pragma unroll
    for (int s = 0; s < 4; ++s)
      #pragma unroll
      for (int oc = 0; oc < 16; ++oc) acc[s][oc] = 0.f;

    for (int ic = 0; ic < 16; ++ic) {
      #pragma unroll
      for (int di = 0; di < 3; ++di) {
        float iv[4][3];
        #pragma unroll
        for (int s = 0; s < 4; ++s) {
            int rr = r0 + 8*s + di;
            #pragma unroll
            for (int dj = 0; dj < 3; ++dj) iv[s][dj] = sin[ic][rr][cq + dj];
        }
        #pragma unroll
        for (int dj = 0; dj < 3; ++dj) {
            const float4* wp = reinterpret_cast<const float4*>(&sw[ic*9 + di*3 + dj][0]);
            float4 w0 = wp[0], w1 = wp[1], w2 = wp[2], w3 = wp[3];
            float wr[16] = {w0.x,w0.y,w0.z,w0.w, w1.x,w1.y,w1.z,w1.w,
                            w2.x,w2.y,w2.z,w2.w, w3.x,w3.y,w3.z,w3.w};
            #pragma unroll
            for (int s = 0; s < 4; ++s) {
                float v = iv[s][dj];
                #pragma unroll
                for (int oc = 0; oc < 16; ++oc) acc[s][oc] += v * wr[oc];
            }
        }
      }
    }

    #pragma unroll
    for (int s = 0; s < 4; ++s) {
        int pi = i0 + r0 + 8*s, pj = j0 + cq;
        #pragma unroll
        for (int oc = 0; oc < 16; ++oc)
            c2[(b*16 + oc)*IMG + pi*128 + pj] = fmaxf(acc[s][oc] + sb[oc], 0.f);
    }
}

// ---------------------------------------------------------------------------
// Kernel 4: fcc split-K partials. Each block owns a 512-wide K slice,
// computes the full 64x128 output tile for that slice.
// ---------------------------------------------------------------------------
__global__ __launch_bounds__(256) void fcc_partial(
    const float* __restrict__ c2flat,   // (64, 262144)
    const float* __restrict__ W,        // (262144, 128)
    float* __restrict__ partials)       // (512, 64*128)
{
    __shared__ float sA[64][FCC_KS];    // 16 KB
    __shared__ float sW[FCC_KS][128];   // 32 KB
    int tid = threadIdx.x;
    int blk = blockIdx.x;
    int k0  = blk * FCC_KRANGE;
    int bq  = tid >> 5;                 // 0..7 -> batches bq*8 .. bq*8+7
    int nq  = tid & 31;                 // cols nq*4 .. nq*4+3
    float acc[8][4] = {};

    for (int kc = 0; kc < FCC_KRANGE; kc += FCC_KS) {
        __syncthreads();
        // A: 64 rows x 64 k  (each thread: 16 consecutive floats of one row)
        {
            int row = tid >> 2;
            int kk4 = (tid & 3) * 16;
            const float4* s4 = reinterpret_cast<const float4*>(
                c2flat + (size_t)row*FCC_K + k0 + kc + kk4);
            float4* dst = reinterpret_cast<float4*>(&sA[row][kk4]);
            dst[0] = s4[0]; dst[1] = s4[1]; dst[2] = s4[2]; dst[3] = s4[3];
        }
        // W: 64 rows x 128 cols (contiguous 32 KB)
        {
            const float4* s4 = reinterpret_cast<const float4*>(W + (size_t)(k0 + kc)*128);
            float4* d4 = reinterpret_cast<float4*>(&sW[0][0]);
            #pragma unroll
            for (int t = 0; t < 8; ++t) d4[tid + t*256] = s4[tid + t*256];
        }
        __syncthreads();

        #pragma unroll 4
        for (int kk = 0; kk < FCC_KS; ++kk) {
            float4 wv = *reinterpret_cast<const float4*>(&sW[kk][nq*4]);
            #pragma unroll
            for (int i = 0; i < 8; ++i) {
                float a = sA[bq*8 + i][kk];
                acc[i][0] += a * wv.x;
                acc[i][1] += a * wv.y;
                acc[i][2] += a * wv.z;
                acc[i][3] += a * wv.w;
            }
        }
    }

    float* p = partials + (size_t)blk * 8192;
    #pragma unroll
    for (int i = 0; i < 8; ++i) {
        int b = bq*8 + i;
        float4 v = {acc[i][0], acc[i][1], acc[i][2], acc[i][3]};
        *reinterpret_cast<float4*>(&p[b*128 + nq*4]) = v;
    }
}

// ---------------------------------------------------------------------------
// Kernel 5: reduce partials -> cvec = relu(sum + bias)
// ---------------------------------------------------------------------------
__global__ __launch_bounds__(256) void fcc_reduce(
    const float* __restrict__ partials,
    const float* __restrict__ bias,     // (128)
    float* __restrict__ cvec)           // (64,128)
{
    int o = blockIdx.x * 256 + threadIdx.x;   // 0..8191
    float s = 0.f;
    for (int p = 0; p < FCC_BLOCKS; ++p) s += partials[(size_t)p*8192 + o];
    cvec[o] = fmaxf(s + bias[o & 127], 0.f);
}

// ---------------------------------------------------------------------------
// Kernel 6: head — concat(c,g) -> fc1 relu -> fc2 relu -> fc3 sigmoid
// One block per batch row.
// ---------------------------------------------------------------------------
__global__ __launch_bounds__(128) void head_kernel(
    const float* __restrict__ cvec, const float* __restrict__ g,
    const float* __restrict__ w1, const float* __restrict__ bb1,  // (256,128),(128)
    const float* __restrict__ w2, const float* __restrict__ bb2,  // (128,64),(64)
    const float* __restrict__ w3, const float* __restrict__ bb3,  // (64,2),(2)
    float* __restrict__ out)                                      // (64,2)
{
    __shared__ float sx[256], sh[128], s2[64];
    int b = blockIdx.x, tid = threadIdx.x;
    sx[tid]       = cvec[b*128 + tid];
    sx[128 + tid] = g[b*128 + tid];
    __syncthreads();
    {
        float acc = bb1[tid];
        for (int k = 0; k < 256; ++k) acc += sx[k] * w1[k*128 + tid];
        sh[tid] = fmaxf(acc, 0.f);
    }
    __syncthreads();
    if (tid < 64) {
        float acc = bb2[tid];
        for (int k = 0; k < 128; ++k) acc += sh[k] * w2[k*64 + tid];
        s2[tid] = fmaxf(acc, 0.f);
    }
    __syncthreads();
    if (tid < 2) {
        float acc = bb3[tid];
        for (int k = 0; k < 64; ++k) acc += s2[k] * w3[k*2 + tid];
        out[b*2 + tid] = 1.f / (1.f + __expf(-acc));
    }
}

// ---------------------------------------------------------------------------
extern "C" void kernel_launch(void* const* d_in, const int* in_sizes, int n_in,
                              void* d_out, int out_size, void* d_ws, size_t ws_size,
                              hipStream_t stream)
{
    const float* x1      = (const float*)d_in[0];
    const float* x2      = (const float*)d_in[1];
    const float* gcn1_w  = (const float*)d_in[2];
    const float* gcn1_b  = (const float*)d_in[3];
    const float* gcn2_w  = (const float*)d_in[4];
    const float* gcn2_b  = (const float*)d_in[5];
    const float* fcg_w   = (const float*)d_in[6];
    const float* fcg_b   = (const float*)d_in[7];
    const float* conv1_w = (const float*)d_in[8];
    const float* conv1_b = (const float*)d_in[9];
    const float* conv2_w = (const float*)d_in[10];
    const float* conv2_b = (const float*)d_in[11];
    const float* fcc_w   = (const float*)d_in[12];
    const float* fcc_b   = (const float*)d_in[13];
    const float* fc1_w   = (const float*)d_in[14];
    const float* fc1_b   = (const float*)d_in[15];
    const float* fc2_w   = (const float*)d_in[16];
    const float* fc2_b   = (const float*)d_in[17];
    const float* fc3_w   = (const float*)d_in[18];
    const float* fc3_b   = (const float*)d_in[19];
    float* out = (float*)d_out;

    // workspace layout (floats)
    float* ws = (float*)d_ws;
    float* h1       = ws;                      // 81920
    float* g        = h1 + 81920;              // 8192
    float* c1       = g + 8192;                // 16777216
    float* c2       = c1 + 16777216;           // 16777216
    float* partials = c2 + 16777216;           // 512*8192 = 4194304
    float* cvec     = partials + 4194304;      // 8192
    // total = 37,847,040 floats ~= 151.4 MB

    gcn_kernel<<<1, 1024, 0, stream>>>(x1, gcn1_w, gcn1_b, gcn2_w, gcn2_b,
                                       fcg_w, fcg_b, h1, g);
    conv1_kernel<<<4096, 256, 0, stream>>>(x2, conv1_w, conv1_b, c1);
    conv2_kernel<<<1024, 256, 0, stream>>>(c1, conv2_w, conv2_b, c2);
    fcc_partial<<<FCC_BLOCKS, 256, 0, stream>>>(c2, fcc_w, partials);
    fcc_reduce<<<32, 256, 0, stream>>>(partials, fcc_b, cvec);
    head_kernel<<<64, 128, 0, stream>>>(cvec, g, fc1_w, fc1_b, fc2_w, fc2_b,
                                        fc3_w, fc3_b, out);
}

// Round 2
// 185.218 us; speedup vs baseline: 1.9146x; 1.9146x over previous
//
#include <hip/hip_runtime.h>
#include <hip/hip_bf16.h>

// ---------------------------------------------------------------------------
// Model: GCN chain -> fcg  ||  conv1 -> conv2(MFMA) -> fcc  -> concat -> head
// B=64, K(nodes)=128, N_BAND=5, HW=128, CH=16
// ---------------------------------------------------------------------------

#define NROWS   8192      // B*K
#define IMG     16384     // 128*128
#define FCC_K   262144    // 16*128*128
#define FCC_BLOCKS 512
#define FCC_KRANGE 512    // FCC_K / FCC_BLOCKS
#define FCC_KS  64        // LDS sub-chunk

typedef __attribute__((ext_vector_type(8))) short bf16x8;
typedef __attribute__((ext_vector_type(4))) float f32x4;

// RNE float->bf16 bits (finite inputs only)
__device__ __forceinline__ unsigned short f2bf(float f) {
    unsigned u = __float_as_uint(f);
    unsigned r = (u + 0x7FFFu + ((u >> 16) & 1u)) >> 16;
    return (unsigned short)r;
}

// ---------------------------------------------------------------------------
// Kernel 1: full GCN chain + fcg, single block (1024 threads).
// ---------------------------------------------------------------------------
__global__ __launch_bounds__(1024) void gcn_kernel(
    const float* __restrict__ x1,    // (8192,5)
    const float* __restrict__ W1,    // (5,10)
    const float* __restrict__ b1,    // (10)
    const float* __restrict__ W2,    // (10,1)
    const float* __restrict__ b2,    // (1)
    const float* __restrict__ fcgW,  // (128,128)
    const float* __restrict__ fcgb,  // (128)
    float* __restrict__ h1,          // ws: 8192*10
    float* __restrict__ g)           // ws: 64*128
{
    __shared__ float sW1[50], sb1[10], sW2[10], smean[10];
    __shared__ float sh2[NROWS];     // 32 KB
    int tid = threadIdx.x;
    if (tid < 50) sW1[tid] = W1[tid];
    if (tid < 10) { sb1[tid] = b1[tid]; sW2[tid] = W2[tid]; }
    __syncthreads();

    for (int r = tid; r < NROWS; r += 1024) {
        float x[5];
        #pragma unroll
        for (int f = 0; f < 5; ++f) x[f] = x1[r*5 + f];
        #pragma unroll
        for (int o = 0; o < 10; ++o) {
            float y = 0.f;
            #pragma unroll
            for (int f = 0; f < 5; ++f) y += x[f] * sW1[f*10 + o];
            if (r >= 128) y = fmaxf(y + sb1[o], 0.f);
            h1[r*10 + o] = y;
        }
    }
    __syncthreads();

    if (tid < 10) {
        float s = 0.f;
        for (int r = 0; r < 128; ++r) s += h1[r*10 + tid];
        smean[tid] = fmaxf(s * (1.f/128.f) + sb1[tid], 0.f);
    }
    __syncthreads();

    for (int idx = tid; idx < 128*10; idx += 1024)
        h1[idx] = smean[idx % 10];
    __syncthreads();

    for (int r = tid; r < NROWS; r += 1024) {
        float y = 0.f;
        #pragma unroll
        for (int f = 0; f < 10; ++f) y += h1[r*10 + f] * sW2[f];
        if (r >= 128) y = fmaxf(y + b2[0], 0.f);
        sh2[r] = y;
    }
    __syncthreads();

    if (tid == 0) {
        float s = 0.f;
        for (int r = 0; r < 128; ++r) s += sh2[r];
        float v = fmaxf(s * (1.f/128.f) + b2[0], 0.f);
        for (int r = 0; r < 128; ++r) sh2[r] = v;
    }
    __syncthreads();

    for (int o = tid; o < 64*128; o += 1024) {
        int b = o >> 7, n = o & 127;
        float acc = fcgb[n];
        const float* h2row = &sh2[b*128];
        for (int k = 0; k < 128; ++k) acc += h2row[k] * fcgW[k*128 + n];
        g[o] = fmaxf(acc, 0.f);
    }
}

// ---------------------------------------------------------------------------
// Kernel 2: conv1 (1 -> 16 ch, 3x3 SAME, relu). Thread per pixel.
// Output: bf16 in [b][row][col][ic] layout (ic contiguous) for conv2 MFMA.
// ---------------------------------------------------------------------------
__global__ __launch_bounds__(256) void conv1_kernel(
    const float* __restrict__ x2,    // (64,128,128)
    const float* __restrict__ w,     // (16,1,3,3)
    const float* __restrict__ bias,  // (16)
    unsigned short* __restrict__ c1bf) // (64,128,128,16) bf16
{
    __shared__ float sw[144], sb[16];
    int tid = threadIdx.x;
    if (tid < 144) sw[tid] = w[tid];
    if (tid < 16)  sb[tid] = bias[tid];
    __syncthreads();

    int gidx = blockIdx.x * 256 + tid;      // 0 .. 64*16384
    int b = gidx >> 14;
    int p = gidx & (IMG - 1);
    int i = p >> 7, j = p & 127;
    const float* xb = x2 + b * IMG;

    float in[3][3];
    #pragma unroll
    for (int di = 0; di < 3; ++di)
      #pragma unroll
      for (int dj = 0; dj < 3; ++dj) {
          int ii = i + di - 1, jj = j + dj - 1;
          in[di][dj] = (ii >= 0 && ii < 128 && jj >= 0 && jj < 128)
                       ? xb[ii*128 + jj] : 0.f;
      }

    typedef __attribute__((ext_vector_type(8))) unsigned short us8;
    us8 o0, o1;
    #pragma unroll
    for (int oc = 0; oc < 16; ++oc) {
        float acc = sb[oc];
        #pragma unroll
        for (int di = 0; di < 3; ++di)
          #pragma unroll
          for (int dj = 0; dj < 3; ++dj)
              acc += in[di][dj] * sw[oc*9 + di*3 + dj];
        unsigned short bits = f2bf(fmaxf(acc, 0.f));
        if (oc < 8) o0[oc] = bits; else o1[oc - 8] = bits;
    }
    unsigned short* dst = c1bf + (size_t)gidx * 16;
    *reinterpret_cast<us8*>(dst)     = o0;
    *reinterpret_cast<us8*>(dst + 8) = o1;
}

// ---------------------------------------------------------------------------
// Kernel 3: conv2 (16 -> 16 ch, 3x3 SAME, relu) as bf16 MFMA implicit GEMM.
// Block: 1 image x 4 output rows (4 waves, 1 row each, 8x 16-pixel tiles).
// K = 16ic x 9 taps -> 5 MFMAs of 16x16x32 per tile (2 taps per MFMA,
// tap selected per lane-group; 9th tap zero-padded in B).
// A-frag: row=lane&15 (pixel), k=(lane>>4)*8+e. B-frag: col=lane&15 (oc).
// C/D: col=lane&15 (oc), row=(lane>>4)*4+reg (pixel).
// ---------------------------------------------------------------------------
__global__ __launch_bounds__(256) void conv2_kernel(
    const unsigned short* __restrict__ c1bf, // (64,128,128,16) bf16
    const float* __restrict__ w,             // (16,16,3,3)
    const float* __restrict__ bias,          // (16)
    float* __restrict__ c2)                  // (64,16,128,128) fp32
{
    __shared__ unsigned short sin[6*130*16];  // 24,960 B halo tile [rr][cc][ic]
    __shared__ unsigned short sB[5*512];      // 5,120 B  per-lane B-frags

    int tid = threadIdx.x;
    int blk = blockIdx.x;                     // 64 images * 32 row-groups
    int b   = blk >> 5;
    int R0  = (blk & 31) * 4;

    // --- pack B-fragments: sB[q][lane][e] = w[oc=lane&15][ic=k&15][dd=2q+(k>>4)]
    for (int idx = tid; idx < 2560; idx += 256) {
        int q   = idx >> 9;
        int rem = idx & 511;
        int l   = rem >> 3;
        int e   = rem & 7;
        int gg  = l >> 4;
        int k   = gg * 8 + e;          // 0..31
        int oc  = l & 15;
        int ic  = k & 15;
        int dd  = 2*q + (k >> 4);
        unsigned short bits = 0;
        if (dd < 9) bits = f2bf(w[oc*144 + ic*9 + dd]);
        sB[idx] = bits;
    }
    // --- zero halo columns (cc=0 and cc=129, all 6 rows, 16 ic)
    if (tid < 192) {
        int rr = tid >> 5, rem = tid & 31;
        int cc = (rem < 16) ? 0 : 129;
        int ic = rem & 15;
        sin[(rr*130 + cc)*16 + ic] = 0;
    }
    // --- stage input halo rows: image rows R0-1 .. R0+4
    {
        const unsigned short* c1b = c1bf + (size_t)b * IMG * 16;
        for (int rr = 0; rr < 6; ++rr) {
            int ri = R0 - 1 + rr;
            uint4 v = {0u,0u,0u,0u};
            if (ri >= 0 && ri < 128)
                v = *reinterpret_cast<const uint4*>(c1b + (size_t)ri*128*16 + tid*8);
            *reinterpret_cast<uint4*>(&sin[(rr*130 + 1)*16 + tid*8]) = v;
        }
    }
    __syncthreads();

    int lane = tid & 63;
    int wv   = tid >> 6;          // wave id -> output row R0+wv
    int ln   = lane & 15;
    int g    = lane >> 4;
    int ghalf = g & 1;

    // per-lane per-q LDS element base for A-frag (add t*256 per tile)
    int aoff[5];
    #pragma unroll
    for (int q = 0; q < 5; ++q) {
        int dd = 2*q + (g >> 1);
        if (dd > 8) dd = 8;       // B is zero there; any in-range addr ok
        int di = dd / 3, dj = dd % 3;
        aoff[q] = ((wv + di)*130 + ln + dj)*16 + ghalf*8;
    }

    // B-fragments to registers (block-lifetime)
    bf16x8 bf[5];
    #pragma unroll
    for (int q = 0; q < 5; ++q)
        bf[q] = *reinterpret_cast<const bf16x8*>(&sB[q*512 + lane*8]);

    float bias_oc = bias[ln];
    int r = R0 + wv;
    float* outbase = c2 + ((size_t)b*16 + ln)*IMG + r*128;

    #pragma unroll
    for (int t = 0; t < 8; ++t) {
        f32x4 acc = {0.f, 0.f, 0.f, 0.f};
        #pragma unroll
        for (int q = 0; q < 5; ++q) {
            bf16x8 a = *reinterpret_cast<const bf16x8*>(&sin[aoff[q] + t*256]);
            acc = __builtin_amdgcn_mfma_f32_16x16x32_bf16(a, bf[q], acc, 0, 0, 0);
        }
        int pc = t*16 + g*4;
        #pragma unroll
        for (int reg = 0; reg < 4; ++reg)
            outbase[pc + reg] = fmaxf(acc[reg] + bias_oc, 0.f);
    }
}

// ---------------------------------------------------------------------------
// Kernel 4: fcc split-K partials (fp32 VALU).
// ---------------------------------------------------------------------------
__global__ __launch_bounds__(256) void fcc_partial(
    const float* __restrict__ c2flat,   // (64, 262144)
    const float* __restrict__ W,        // (262144, 128)
    float* __restrict__ partials)       // (512, 64*128)
{
    __shared__ float sA[64][FCC_KS];    // 16 KB
    __shared__ float sW[FCC_KS][128];   // 32 KB
    int tid = threadIdx.x;
    int blk = blockIdx.x;
    int k0  = blk * FCC_KRANGE;
    int bq  = tid >> 5;
    int nq  = tid & 31;
    float acc[8][4] = {};

    for (int kc = 0; kc < FCC_KRANGE; kc += FCC_KS) {
        __syncthreads();
        {
            int row = tid >> 2;
            int kk4 = (tid & 3) * 16;
            const float4* s4 = reinterpret_cast<const float4*>(
                c2flat + (size_t)row*FCC_K + k0 + kc + kk4);
            float4* dst = reinterpret_cast<float4*>(&sA[row][kk4]);
            dst[0] = s4[0]; dst[1] = s4[1]; dst[2] = s4[2]; dst[3] = s4[3];
        }
        {
            const float4* s4 = reinterpret_cast<const float4*>(W + (size_t)(k0 + kc)*128);
            float4* d4 = reinterpret_cast<float4*>(&sW[0][0]);
            #pragma unroll
            for (int t = 0; t < 8; ++t) d4[tid + t*256] = s4[tid + t*256];
        }
        __syncthreads();

        #pragma unroll 4
        for (int kk = 0; kk < FCC_KS; ++kk) {
            float4 wv = *reinterpret_cast<const float4*>(&sW[kk][nq*4]);
            #pragma unroll
            for (int i = 0; i < 8; ++i) {
                float a = sA[bq*8 + i][kk];
                acc[i][0] += a * wv.x;
                acc[i][1] += a * wv.y;
                acc[i][2] += a * wv.z;
                acc[i][3] += a * wv.w;
            }
        }
    }

    float* p = partials + (size_t)blk * 8192;
    #pragma unroll
    for (int i = 0; i < 8; ++i) {
        int b = bq*8 + i;
        float4 v = {acc[i][0], acc[i][1], acc[i][2], acc[i][3]};
        *reinterpret_cast<float4*>(&p[b*128 + nq*4]) = v;
    }
}

// ---------------------------------------------------------------------------
// Kernel 5: reduce partials -> cvec = relu(sum + bias)
// ---------------------------------------------------------------------------
__global__ __launch_bounds__(256) void fcc_reduce(
    const float* __restrict__ partials,
    const float* __restrict__ bias,
    float* __restrict__ cvec)
{
    int o = blockIdx.x * 256 + threadIdx.x;   // 0..8191
    float s = 0.f;
    for (int p = 0; p < FCC_BLOCKS; ++p) s += partials[(size_t)p*8192 + o];
    cvec[o] = fmaxf(s + bias[o & 127], 0.f);
}

// ---------------------------------------------------------------------------
// Kernel 6: head — concat(c,g) -> fc1 relu -> fc2 relu -> fc3 sigmoid
// ---------------------------------------------------------------------------
__global__ __launch_bounds__(128) void head_kernel(
    const float* __restrict__ cvec, const float* __restrict__ g,
    const float* __restrict__ w1, const float* __restrict__ bb1,
    const float* __restrict__ w2, const float* __restrict__ bb2,
    const float* __restrict__ w3, const float* __restrict__ bb3,
    float* __restrict__ out)
{
    __shared__ float sx[256], sh[128], s2[64];
    int b = blockIdx.x, tid = threadIdx.x;
    sx[tid]       = cvec[b*128 + tid];
    sx[128 + tid] = g[b*128 + tid];
    __syncthreads();
    {
        float acc = bb1[tid];
        for (int k = 0; k < 256; ++k) acc += sx[k] * w1[k*128 + tid];
        sh[tid] = fmaxf(acc, 0.f);
    }
    __syncthreads();
    if (tid < 64) {
        float acc = bb2[tid];
        for (int k = 0; k < 128; ++k) acc += sh[k] * w2[k*64 + tid];
        s2[tid] = fmaxf(acc, 0.f);
    }
    __syncthreads();
    if (tid < 2) {
        float acc = bb3[tid];
        for (int k = 0; k < 64; ++k) acc += s2[k] * w3[k*2 + tid];
        out[b*2 + tid] = 1.f / (1.f + __expf(-acc));
    }
}

// ---------------------------------------------------------------------------
extern "C" void kernel_launch(void* const* d_in, const int* in_sizes, int n_in,
                              void* d_out, int out_size, void* d_ws, size_t ws_size,
                              hipStream_t stream)
{
    const float* x1      = (const float*)d_in[0];
    const float* x2      = (const float*)d_in[1];
    const float* gcn1_w  = (const float*)d_in[2];
    const float* gcn1_b  = (const float*)d_in[3];
    const float* gcn2_w  = (const float*)d_in[4];
    const float* gcn2_b  = (const float*)d_in[5];
    const float* fcg_w   = (const float*)d_in[6];
    const float* fcg_b   = (const float*)d_in[7];
    const float* conv1_w = (const float*)d_in[8];
    const float* conv1_b = (const float*)d_in[9];
    const float* conv2_w = (const float*)d_in[10];
    const float* conv2_b = (const float*)d_in[11];
    const float* fcc_w   = (const float*)d_in[12];
    const float* fcc_b   = (const float*)d_in[13];
    const float* fc1_w   = (const float*)d_in[14];
    const float* fc1_b   = (const float*)d_in[15];
    const float* fc2_w   = (const float*)d_in[16];
    const float* fc2_b   = (const float*)d_in[17];
    const float* fc3_w   = (const float*)d_in[18];
    const float* fc3_b   = (const float*)d_in[19];
    float* out = (float*)d_out;

    // workspace layout
    float* ws = (float*)d_ws;
    float* h1       = ws;                         // 81,920 f
    float* g        = h1 + 81920;                 // 8,192 f
    unsigned short* c1bf = (unsigned short*)(g + 8192);  // 16,777,216 bf16
    float* c2       = (float*)(c1bf + 16777216);  // 16,777,216 f
    float* partials = c2 + 16777216;              // 4,194,304 f
    float* cvec     = partials + 4194304;         // 8,192 f
    // total ~117.9 MB

    gcn_kernel<<<1, 1024, 0, stream>>>(x1, gcn1_w, gcn1_b, gcn2_w, gcn2_b,
                                       fcg_w, fcg_b, h1, g);
    conv1_kernel<<<4096, 256, 0, stream>>>(x2, conv1_w, conv1_b, c1bf);
    conv2_kernel<<<2048, 256, 0, stream>>>(c1bf, conv2_w, conv2_b, c2);
    fcc_partial<<<FCC_BLOCKS, 256, 0, stream>>>(c2, fcc_w, partials);
    fcc_reduce<<<32, 256, 0, stream>>>(partials, fcc_b, cvec);
    head_kernel<<<64, 128, 0, stream>>>(cvec, g, fc1_w, fc1_b, fc2_w, fc2_b,
                                        fc3_w, fc3_b, out);
}

// Round 3
// 128.875 us; speedup vs baseline: 2.7516x; 1.4372x over previous
//
#include <hip/hip_runtime.h>
#include <hip/hip_bf16.h>

// ---------------------------------------------------------------------------
// Model: GCN chain -> fcg  ||  conv1 -> conv2(MFMA) -> fcc(MFMA) -> head
// B=64, K(nodes)=128, N_BAND=5, HW=128, CH=16
// ---------------------------------------------------------------------------

#define NROWS   8192      // B*K
#define IMG     16384     // 128*128
#define FCC_K   262144    // 16*128*128
#define FCC_BLOCKS 1024
#define FCC_KRANGE 256    // FCC_K / FCC_BLOCKS
#define FCC_CHUNK 128     // K per LDS stage
#define WPAD 132          // padded row length (shorts) for sW

typedef __attribute__((ext_vector_type(8))) short bf16x8;
typedef __attribute__((ext_vector_type(4))) float f32x4;
typedef __attribute__((ext_vector_type(4))) unsigned short us4;
typedef __attribute__((ext_vector_type(8))) unsigned short us8;

// RNE float->bf16 bits (finite inputs only)
__device__ __forceinline__ unsigned short f2bf(float f) {
    unsigned u = __float_as_uint(f);
    unsigned r = (u + 0x7FFFu + ((u >> 16) & 1u)) >> 16;
    return (unsigned short)r;
}

// ---------------------------------------------------------------------------
// Kernel 1: GCN chain (phases 1-5), single block. h2 written to ws.
// ---------------------------------------------------------------------------
__global__ __launch_bounds__(1024) void gcn_kernel(
    const float* __restrict__ x1,    // (8192,5)
    const float* __restrict__ W1,    // (5,10)
    const float* __restrict__ b1,    // (10)
    const float* __restrict__ W2,    // (10,1)
    const float* __restrict__ b2,    // (1)
    float* __restrict__ h1,          // ws: 8192*10
    float* __restrict__ h2)          // ws: 8192
{
    __shared__ float sW1[50], sb1[10], sW2[10], smean[10];
    __shared__ float sh2[NROWS];     // 32 KB
    int tid = threadIdx.x;
    if (tid < 50) sW1[tid] = W1[tid];
    if (tid < 10) { sb1[tid] = b1[tid]; sW2[tid] = W2[tid]; }
    __syncthreads();

    for (int r = tid; r < NROWS; r += 1024) {
        float x[5];
        #pragma unroll
        for (int f = 0; f < 5; ++f) x[f] = x1[r*5 + f];
        #pragma unroll
        for (int o = 0; o < 10; ++o) {
            float y = 0.f;
            #pragma unroll
            for (int f = 0; f < 5; ++f) y += x[f] * sW1[f*10 + o];
            if (r >= 128) y = fmaxf(y + sb1[o], 0.f);
            h1[r*10 + o] = y;
        }
    }
    __syncthreads();

    if (tid < 10) {
        float s = 0.f;
        for (int r = 0; r < 128; ++r) s += h1[r*10 + tid];
        smean[tid] = fmaxf(s * (1.f/128.f) + sb1[tid], 0.f);
    }
    __syncthreads();

    for (int idx = tid; idx < 128*10; idx += 1024)
        h1[idx] = smean[idx % 10];
    __syncthreads();

    for (int r = tid; r < NROWS; r += 1024) {
        float y = 0.f;
        #pragma unroll
        for (int f = 0; f < 10; ++f) y += h1[r*10 + f] * sW2[f];
        if (r >= 128) y = fmaxf(y + b2[0], 0.f);
        sh2[r] = y;
    }
    __syncthreads();

    if (tid == 0) {
        float s = 0.f;
        for (int r = 0; r < 128; ++r) s += sh2[r];
        float v = fmaxf(s * (1.f/128.f) + b2[0], 0.f);
        for (int r = 0; r < 128; ++r) sh2[r] = v;
    }
    __syncthreads();

    for (int r = tid; r < NROWS; r += 1024) h2[r] = sh2[r];
}

// ---------------------------------------------------------------------------
// Kernel 1b: g = relu(h2 @ fcgW + fcgb), one block per batch row.
// ---------------------------------------------------------------------------
__global__ __launch_bounds__(128) void fcg_kernel(
    const float* __restrict__ h2,    // (64,128)
    const float* __restrict__ fcgW,  // (128,128)
    const float* __restrict__ fcgb,  // (128)
    float* __restrict__ g)           // (64,128)
{
    __shared__ float sh[128];
    int b = blockIdx.x, t = threadIdx.x;
    sh[t] = h2[b*128 + t];
    __syncthreads();
    float acc = fcgb[t];
    #pragma unroll 8
    for (int k = 0; k < 128; ++k) acc += sh[k] * fcgW[k*128 + t];
    g[b*128 + t] = fmaxf(acc, 0.f);
}

// ---------------------------------------------------------------------------
// Kernel 2: conv1 (1 -> 16 ch, 3x3 SAME, relu). Thread per pixel.
// Output: bf16 in [b][row][col][ic] layout (ic contiguous) for conv2 MFMA.
// ---------------------------------------------------------------------------
__global__ __launch_bounds__(256) void conv1_kernel(
    const float* __restrict__ x2,    // (64,128,128)
    const float* __restrict__ w,     // (16,1,3,3)
    const float* __restrict__ bias,  // (16)
    unsigned short* __restrict__ c1bf) // (64,128,128,16) bf16
{
    __shared__ float sw[144], sb[16];
    int tid = threadIdx.x;
    if (tid < 144) sw[tid] = w[tid];
    if (tid < 16)  sb[tid] = bias[tid];
    __syncthreads();

    int gidx = blockIdx.x * 256 + tid;      // 0 .. 64*16384
    int b = gidx >> 14;
    int p = gidx & (IMG - 1);
    int i = p >> 7, j = p & 127;
    const float* xb = x2 + b * IMG;

    float in[3][3];
    #pragma unroll
    for (int di = 0; di < 3; ++di)
      #pragma unroll
      for (int dj = 0; dj < 3; ++dj) {
          int ii = i + di - 1, jj = j + dj - 1;
          in[di][dj] = (ii >= 0 && ii < 128 && jj >= 0 && jj < 128)
                       ? xb[ii*128 + jj] : 0.f;
      }

    us8 o0, o1;
    #pragma unroll
    for (int oc = 0; oc < 16; ++oc) {
        float acc = sb[oc];
        #pragma unroll
        for (int di = 0; di < 3; ++di)
          #pragma unroll
          for (int dj = 0; dj < 3; ++dj)
              acc += in[di][dj] * sw[oc*9 + di*3 + dj];
        unsigned short bits = f2bf(fmaxf(acc, 0.f));
        if (oc < 8) o0[oc] = bits; else o1[oc - 8] = bits;
    }
    unsigned short* dst = c1bf + (size_t)gidx * 16;
    *reinterpret_cast<us8*>(dst)     = o0;
    *reinterpret_cast<us8*>(dst + 8) = o1;
}

// ---------------------------------------------------------------------------
// Kernel 3: conv2 (16 -> 16 ch, 3x3 SAME, relu) as bf16 MFMA implicit GEMM.
// Output now bf16 (feeds fcc's A operand directly).
// ---------------------------------------------------------------------------
__global__ __launch_bounds__(256) void conv2_kernel(
    const unsigned short* __restrict__ c1bf, // (64,128,128,16) bf16
    const float* __restrict__ w,             // (16,16,3,3)
    const float* __restrict__ bias,          // (16)
    unsigned short* __restrict__ c2bf)       // (64,16,128,128) bf16
{
    __shared__ unsigned short sin[6*130*16];  // 24,960 B halo tile [rr][cc][ic]
    __shared__ unsigned short sB[5*512];      // 5,120 B  per-lane B-frags

    int tid = threadIdx.x;
    int blk = blockIdx.x;                     // 64 images * 32 row-groups
    int b   = blk >> 5;
    int R0  = (blk & 31) * 4;

    for (int idx = tid; idx < 2560; idx += 256) {
        int q   = idx >> 9;
        int rem = idx & 511;
        int l   = rem >> 3;
        int e   = rem & 7;
        int gg  = l >> 4;
        int k   = gg * 8 + e;          // 0..31
        int oc  = l & 15;
        int ic  = k & 15;
        int dd  = 2*q + (k >> 4);
        unsigned short bits = 0;
        if (dd < 9) bits = f2bf(w[oc*144 + ic*9 + dd]);
        sB[idx] = bits;
    }
    if (tid < 192) {
        int rr = tid >> 5, rem = tid & 31;
        int cc = (rem < 16) ? 0 : 129;
        int ic = rem & 15;
        sin[(rr*130 + cc)*16 + ic] = 0;
    }
    {
        const unsigned short* c1b = c1bf + (size_t)b * IMG * 16;
        for (int rr = 0; rr < 6; ++rr) {
            int ri = R0 - 1 + rr;
            uint4 v = {0u,0u,0u,0u};
            if (ri >= 0 && ri < 128)
                v = *reinterpret_cast<const uint4*>(c1b + (size_t)ri*128*16 + tid*8);
            *reinterpret_cast<uint4*>(&sin[(rr*130 + 1)*16 + tid*8]) = v;
        }
    }
    __syncthreads();

    int lane = tid & 63;
    int wv   = tid >> 6;          // wave id -> output row R0+wv
    int ln   = lane & 15;
    int g    = lane >> 4;
    int ghalf = g & 1;

    int aoff[5];
    #pragma unroll
    for (int q = 0; q < 5; ++q) {
        int dd = 2*q + (g >> 1);
        if (dd > 8) dd = 8;
        int di = dd / 3, dj = dd % 3;
        aoff[q] = ((wv + di)*130 + ln + dj)*16 + ghalf*8;
    }

    bf16x8 bf[5];
    #pragma unroll
    for (int q = 0; q < 5; ++q)
        bf[q] = *reinterpret_cast<const bf16x8*>(&sB[q*512 + lane*8]);

    float bias_oc = bias[ln];
    int r = R0 + wv;
    unsigned short* outbase = c2bf + ((size_t)b*16 + ln)*IMG + r*128;

    #pragma unroll
    for (int t = 0; t < 8; ++t) {
        f32x4 acc = {0.f, 0.f, 0.f, 0.f};
        #pragma unroll
        for (int q = 0; q < 5; ++q) {
            bf16x8 a = *reinterpret_cast<const bf16x8*>(&sin[aoff[q] + t*256]);
            acc = __builtin_amdgcn_mfma_f32_16x16x32_bf16(a, bf[q], acc, 0, 0, 0);
        }
        int pc = t*16 + g*4;
        #pragma unroll
        for (int reg = 0; reg < 4; ++reg)
            outbase[pc + reg] = f2bf(fmaxf(acc[reg] + bias_oc, 0.f));
    }
}

// ---------------------------------------------------------------------------
// Kernel 4: fcc split-K partials, bf16 MFMA.
// Block: K-slice of 256. LDS: W chunk (128 x 128) as bf16 [128][WPAD=132].
// 4 waves; wave w owns m-rows 16w..16w+15, all 8 n-tiles.
// A-frags straight from global (c2bf is L2/L3-resident).
// ---------------------------------------------------------------------------
__global__ __launch_bounds__(256, 4) void fcc_mfma(
    const unsigned short* __restrict__ c2bf, // (64, 262144) bf16 row-major
    const float* __restrict__ W,             // (262144, 128) fp32
    float* __restrict__ partials)            // (1024, 64*128)
{
    __shared__ unsigned short sW[FCC_CHUNK * WPAD];   // 33,792 B

    int tid  = threadIdx.x;
    int blk  = blockIdx.x;
    int k0   = blk * FCC_KRANGE;
    int lane = tid & 63, wv = tid >> 6;
    int ln   = lane & 15, g = lane >> 4;

    f32x4 acc[8];
    #pragma unroll
    for (int j = 0; j < 8; ++j) acc[j] = (f32x4){0.f,0.f,0.f,0.f};

    int skr = tid >> 5;            // staging row group 0..7
    int sn0 = (tid & 31) * 4;      // staging col

    for (int kc = 0; kc < FCC_KRANGE; kc += FCC_CHUNK) {
        // ---- stage W rows [k0+kc, +128) as bf16 into sW (coalesced) ----
        #pragma unroll 4
        for (int it = 0; it < 16; ++it) {
            int k = skr + it*8;
            float4 v = *reinterpret_cast<const float4*>(
                W + (size_t)(k0 + kc + k)*128 + sn0);
            us4 pk;
            pk[0] = f2bf(v.x); pk[1] = f2bf(v.y);
            pk[2] = f2bf(v.z); pk[3] = f2bf(v.w);
            *reinterpret_cast<us4*>(&sW[k*WPAD + sn0]) = pk;
        }
        __syncthreads();

        // ---- compute: 4 K-steps of 32 ----
        #pragma unroll
        for (int ks = 0; ks < 4; ++ks) {
            const unsigned short* ap = c2bf + (size_t)(16*wv + ln)*FCC_K
                                       + k0 + kc + ks*32 + g*8;
            bf16x8 afrag = *reinterpret_cast<const bf16x8*>(ap);
            int rbase = (ks*32 + g*8) * WPAD;
            #pragma unroll
            for (int j = 0; j < 8; ++j) {
                int col = j*16 + ln;
                bf16x8 bfrag;
                #pragma unroll
                for (int e = 0; e < 8; ++e)
                    bfrag[e] = (short)sW[rbase + e*WPAD + col];
                acc[j] = __builtin_amdgcn_mfma_f32_16x16x32_bf16(afrag, bfrag, acc[j], 0, 0, 0);
            }
        }
        __syncthreads();
    }

    float* p = partials + (size_t)blk * 8192;
    #pragma unroll
    for (int j = 0; j < 8; ++j)
      #pragma unroll
      for (int reg = 0; reg < 4; ++reg) {
          int m = 16*wv + g*4 + reg;
          p[m*128 + j*16 + ln] = acc[j][reg];
      }
}

// ---------------------------------------------------------------------------
// Kernel 5: reduce partials -> cvec = relu(sum + bias).
// 128 blocks; block handles 64 outputs with 4-way K-split + LDS combine.
// ---------------------------------------------------------------------------
__global__ __launch_bounds__(256) void fcc_reduce(
    const float* __restrict__ partials,
    const float* __restrict__ bias,
    float* __restrict__ cvec)
{
    __shared__ float sred[4][64];
    int blk = blockIdx.x;
    int t = threadIdx.x;
    int o = blk*64 + (t & 63);
    int pr = t >> 6;
    float s = 0.f;
    #pragma unroll 4
    for (int p = pr; p < FCC_BLOCKS; p += 4)
        s += partials[(size_t)p*8192 + o];
    sred[pr][t & 63] = s;
    __syncthreads();
    if (t < 64) {
        float v = sred[0][t] + sred[1][t] + sred[2][t] + sred[3][t];
        cvec[o] = fmaxf(v + bias[o & 127], 0.f);
    }
}

// ---------------------------------------------------------------------------
// Kernel 6: head — concat(c,g) -> fc1 relu -> fc2 relu -> fc3 sigmoid
// ---------------------------------------------------------------------------
__global__ __launch_bounds__(128) void head_kernel(
    const float* __restrict__ cvec, const float* __restrict__ g,
    const float* __restrict__ w1, const float* __restrict__ bb1,
    const float* __restrict__ w2, const float* __restrict__ bb2,
    const float* __restrict__ w3, const float* __restrict__ bb3,
    float* __restrict__ out)
{
    __shared__ float sx[256], sh[128], s2[64];
    int b = blockIdx.x, tid = threadIdx.x;
    sx[tid]       = cvec[b*128 + tid];
    sx[128 + tid] = g[b*128 + tid];
    __syncthreads();
    {
        float acc = bb1[tid];
        for (int k = 0; k < 256; ++k) acc += sx[k] * w1[k*128 + tid];
        sh[tid] = fmaxf(acc, 0.f);
    }
    __syncthreads();
    if (tid < 64) {
        float acc = bb2[tid];
        for (int k = 0; k < 128; ++k) acc += sh[k] * w2[k*64 + tid];
        s2[tid] = fmaxf(acc, 0.f);
    }
    __syncthreads();
    if (tid < 2) {
        float acc = bb3[tid];
        for (int k = 0; k < 64; ++k) acc += s2[k] * w3[k*2 + tid];
        out[b*2 + tid] = 1.f / (1.f + __expf(-acc));
    }
}

// ---------------------------------------------------------------------------
extern "C" void kernel_launch(void* const* d_in, const int* in_sizes, int n_in,
                              void* d_out, int out_size, void* d_ws, size_t ws_size,
                              hipStream_t stream)
{
    const float* x1      = (const float*)d_in[0];
    const float* x2      = (const float*)d_in[1];
    const float* gcn1_w  = (const float*)d_in[2];
    const float* gcn1_b  = (const float*)d_in[3];
    const float* gcn2_w  = (const float*)d_in[4];
    const float* gcn2_b  = (const float*)d_in[5];
    const float* fcg_w   = (const float*)d_in[6];
    const float* fcg_b   = (const float*)d_in[7];
    const float* conv1_w = (const float*)d_in[8];
    const float* conv1_b = (const float*)d_in[9];
    const float* conv2_w = (const float*)d_in[10];
    const float* conv2_b = (const float*)d_in[11];
    const float* fcc_w   = (const float*)d_in[12];
    const float* fcc_b   = (const float*)d_in[13];
    const float* fc1_w   = (const float*)d_in[14];
    const float* fc1_b   = (const float*)d_in[15];
    const float* fc2_w   = (const float*)d_in[16];
    const float* fc2_b   = (const float*)d_in[17];
    const float* fc3_w   = (const float*)d_in[18];
    const float* fc3_b   = (const float*)d_in[19];
    float* out = (float*)d_out;

    // workspace layout
    float* ws = (float*)d_ws;
    float* h1       = ws;                          // 81,920 f
    float* h2       = h1 + 81920;                  // 8,192 f
    float* g        = h2 + 8192;                   // 8,192 f
    unsigned short* c1bf = (unsigned short*)(g + 8192);   // 16,777,216 bf16
    unsigned short* c2bf = c1bf + 16777216;               // 16,777,216 bf16
    float* partials = (float*)(c2bf + 16777216);   // 1024*8192 = 8,388,608 f
    float* cvec     = partials + 8388608;          // 8,192 f
    // total ~101 MB

    gcn_kernel<<<1, 1024, 0, stream>>>(x1, gcn1_w, gcn1_b, gcn2_w, gcn2_b, h1, h2);
    fcg_kernel<<<64, 128, 0, stream>>>(h2, fcg_w, fcg_b, g);
    conv1_kernel<<<4096, 256, 0, stream>>>(x2, conv1_w, conv1_b, c1bf);
    conv2_kernel<<<2048, 256, 0, stream>>>(c1bf, conv2_w, conv2_b, c2bf);
    fcc_mfma<<<FCC_BLOCKS, 256, 0, stream>>>(c2bf, fcc_w, partials);
    fcc_reduce<<<128, 256, 0, stream>>>(partials, fcc_b, cvec);
    head_kernel<<<64, 128, 0, stream>>>(cvec, g, fc1_w, fc1_b, fc2_w, fc2_b,
                                        fc3_w, fc3_b, out);
}

// Round 4
// 100.596 us; speedup vs baseline: 3.5251x; 1.2811x over previous
//
#include <hip/hip_runtime.h>
#include <hip/hip_bf16.h>

// ---------------------------------------------------------------------------
// Model: [gcn+fcg fused] || [conv1+conv2 fused, MFMA] -> fcc(MFMA) -> head
// B=64, K(nodes)=128, N_BAND=5, HW=128, CH=16
// ---------------------------------------------------------------------------

#define NROWS   8192      // B*K
#define IMG     16384     // 128*128
#define FCC_K   262144    // 16*128*128
#define FCC_BLOCKS 512
#define FCC_KRANGE 512    // FCC_K / FCC_BLOCKS
#define FCC_CHUNK 128     // K rows of W per LDS stage
#define WPAD 132          // padded row length (shorts) for sW

typedef __attribute__((ext_vector_type(8))) short bf16x8;
typedef __attribute__((ext_vector_type(4))) float f32x4;
typedef __attribute__((ext_vector_type(4))) unsigned short us4;
typedef __attribute__((ext_vector_type(8))) unsigned short us8;

// RNE float->bf16 bits (finite inputs only)
__device__ __forceinline__ unsigned short f2bf(float f) {
    unsigned u = __float_as_uint(f);
    unsigned r = (u + 0x7FFFu + ((u >> 16) & 1u)) >> 16;
    return (unsigned short)r;
}

// ---------------------------------------------------------------------------
// Kernel 1: fused GCN chain + fcg. One block per batch row (64 blocks x 128).
// Rows 0..127 (= batch 0 exactly) get the column-mean treatment -> block-local.
// ---------------------------------------------------------------------------
__global__ __launch_bounds__(128) void gcnfcg_kernel(
    const float* __restrict__ x1,    // (8192,5)
    const float* __restrict__ W1,    // (5,10)
    const float* __restrict__ b1,    // (10)
    const float* __restrict__ W2,    // (10,1)
    const float* __restrict__ b2,    // (1)
    const float* __restrict__ fcgW,  // (128,128)
    const float* __restrict__ fcgb,  // (128)
    float* __restrict__ g)           // (64,128)
{
    __shared__ float sW1[50], sb1[10], sW2[10], smean[10];
    __shared__ float sy1[128][10];   // raw layer-1 rows (block 0 only)
    __shared__ float sh2[128];
    int b = blockIdx.x, t = threadIdx.x;
    if (t < 50) sW1[t] = W1[t];
    if (t < 10) { sb1[t] = b1[t]; sW2[t] = W2[t]; }
    __syncthreads();

    int r = b*128 + t;
    float x[5];
    #pragma unroll
    for (int f = 0; f < 5; ++f) x[f] = x1[r*5 + f];
    float y[10];
    #pragma unroll
    for (int o = 0; o < 10; ++o) {
        float a = 0.f;
        #pragma unroll
        for (int f = 0; f < 5; ++f) a += x[f] * sW1[f*10 + o];
        y[o] = a;
    }

    float h1row[10];
    if (b == 0) {
        #pragma unroll
        for (int o = 0; o < 10; ++o) sy1[t][o] = y[o];
        __syncthreads();
        if (t < 10) {
            float s = 0.f;
            for (int rr = 0; rr < 128; ++rr) s += sy1[rr][t];
            smean[t] = fmaxf(s * (1.f/128.f) + sb1[t], 0.f);
        }
        __syncthreads();
        #pragma unroll
        for (int o = 0; o < 10; ++o) h1row[o] = smean[o];
    } else {
        #pragma unroll
        for (int o = 0; o < 10; ++o) h1row[o] = fmaxf(y[o] + sb1[o], 0.f);
    }

    // layer 2 (10 -> 1). For b==0 all rows share h1row, so mean == value.
    float y2 = 0.f;
    #pragma unroll
    for (int o = 0; o < 10; ++o) y2 += h1row[o] * sW2[o];
    sh2[t] = fmaxf(y2 + b2[0], 0.f);
    __syncthreads();

    // fcg: g[b] = relu(h2_b @ fcgW + fcgb)
    float acc = fcgb[t];
    #pragma unroll 8
    for (int k = 0; k < 128; ++k) acc += sh2[k] * fcgW[k*128 + t];
    g[b*128 + t] = fmaxf(acc, 0.f);
}

// ---------------------------------------------------------------------------
// Kernel 2: fused conv1+conv2 (3x3 SAME, relu both) -> bf16 c2.
// Block: 1 image x 4 output rows. conv1 computed in-block into the LDS halo
// tile (6 rows incl. halo), then conv2 as 5x MFMA 16x16x32 per 16-px tile.
// ---------------------------------------------------------------------------
__global__ __launch_bounds__(256) void conv12_kernel(
    const float* __restrict__ x2,     // (64,128,128)
    const float* __restrict__ w1,     // (16,1,3,3)
    const float* __restrict__ b1,     // (16)
    const float* __restrict__ w2,     // (16,16,3,3)
    const float* __restrict__ b2,     // (16)
    unsigned short* __restrict__ c2bf)// (64,16,128,128) bf16
{
    __shared__ float sx2[8][130];             // 4,160 B  x2 tile (+halo)
    __shared__ unsigned short sin[6*130*16];  // 24,960 B conv1 out [rr][cc][ic]
    __shared__ unsigned short sB[5*512];      // 5,120 B  conv2 B-frags
    __shared__ float sw1[144], sb1v[16];

    int tid = threadIdx.x;
    int blk = blockIdx.x;                     // 64 images * 32 row-groups
    int b   = blk >> 5;
    int R0  = (blk & 31) * 4;

    if (tid < 144) sw1[tid] = w1[tid];
    if (tid < 16)  sb1v[tid] = b1[tid];

    // pack conv2 B-frags: sB[q][lane][e] = w2[oc=lane&15][ic=k&15][dd=2q+(k>>4)]
    for (int idx = tid; idx < 2560; idx += 256) {
        int q   = idx >> 9;
        int rem = idx & 511;
        int l   = rem >> 3;
        int e   = rem & 7;
        int k   = (l >> 4) * 8 + e;    // 0..31
        int oc  = l & 15;
        int ic  = k & 15;
        int dd  = 2*q + (k >> 4);
        unsigned short bits = 0;
        if (dd < 9) bits = f2bf(w2[oc*144 + ic*9 + dd]);
        sB[idx] = bits;
    }
    // zero sin halo columns (cc=0 and cc=129)
    if (tid < 192) {
        int rr = tid >> 5, rem = tid & 31;
        int cc = (rem < 16) ? 0 : 129;
        sin[(rr*130 + cc)*16 + (rem & 15)] = 0;
    }
    // stage x2 rows R0-2 .. R0+5 (zero-padded)
    {
        const float* xb = x2 + (size_t)b * IMG;
        for (int idx = tid; idx < 8*130; idx += 256) {
            int rr = idx / 130, cc = idx - rr*130;
            int ri = R0 - 2 + rr, gj = cc - 1;
            float v = 0.f;
            if (ri >= 0 && ri < 128 && gj >= 0 && gj < 128)
                v = xb[ri*128 + gj];
            sx2[rr][cc] = v;
        }
    }
    __syncthreads();

    // conv1: 6 rows (R0-1..R0+4) x 128 cols x 16 oc -> sin (bf16)
    for (int p = tid; p < 768; p += 256) {
        int rr = p >> 7;            // 0..5 ; conv1 output row = R0-1+rr
        int cc = p & 127;
        int ri1 = R0 - 1 + rr;
        bool valid = (ri1 >= 0 && ri1 < 128);
        float in9[3][3];
        #pragma unroll
        for (int di = 0; di < 3; ++di)
          #pragma unroll
          for (int dj = 0; dj < 3; ++dj)
              in9[di][dj] = sx2[rr + di][cc + dj];
        us8 o0, o1;
        #pragma unroll
        for (int oc = 0; oc < 16; ++oc) {
            float acc = sb1v[oc];
            #pragma unroll
            for (int di = 0; di < 3; ++di)
              #pragma unroll
              for (int dj = 0; dj < 3; ++dj)
                  acc += in9[di][dj] * sw1[oc*9 + di*3 + dj];
            unsigned short bits = valid ? f2bf(fmaxf(acc, 0.f)) : (unsigned short)0;
            if (oc < 8) o0[oc] = bits; else o1[oc - 8] = bits;
        }
        unsigned short* dst = &sin[(rr*130 + cc + 1)*16];
        *reinterpret_cast<us8*>(dst)     = o0;
        *reinterpret_cast<us8*>(dst + 8) = o1;
    }
    __syncthreads();

    // conv2 MFMA
    int lane = tid & 63;
    int wv   = tid >> 6;          // wave id -> output row R0+wv
    int ln   = lane & 15;
    int g    = lane >> 4;
    int ghalf = g & 1;

    int aoff[5];
    #pragma unroll
    for (int q = 0; q < 5; ++q) {
        int dd = 2*q + (g >> 1);
        if (dd > 8) dd = 8;       // B is zero there
        int di = dd / 3, dj = dd % 3;
        aoff[q] = ((wv + di)*130 + ln + dj)*16 + ghalf*8;
    }

    bf16x8 bf[5];
    #pragma unroll
    for (int q = 0; q < 5; ++q)
        bf[q] = *reinterpret_cast<const bf16x8*>(&sB[q*512 + lane*8]);

    float bias_oc = b2[ln];
    int r = R0 + wv;
    unsigned short* outbase = c2bf + ((size_t)b*16 + ln)*IMG + r*128;

    #pragma unroll
    for (int t = 0; t < 8; ++t) {
        f32x4 acc = {0.f, 0.f, 0.f, 0.f};
        #pragma unroll
        for (int q = 0; q < 5; ++q) {
            bf16x8 a = *reinterpret_cast<const bf16x8*>(&sin[aoff[q] + t*256]);
            acc = __builtin_amdgcn_mfma_f32_16x16x32_bf16(a, bf[q], acc, 0, 0, 0);
        }
        int pc = t*16 + g*4;
        #pragma unroll
        for (int reg = 0; reg < 4; ++reg)
            outbase[pc + reg] = f2bf(fmaxf(acc[reg] + bias_oc, 0.f));
    }
}

// ---------------------------------------------------------------------------
// Kernel 3: fcc split-K partials, bf16 MFMA. 512 blocks x K-slice 512.
// ---------------------------------------------------------------------------
__global__ __launch_bounds__(256, 4) void fcc_mfma(
    const unsigned short* __restrict__ c2bf, // (64, 262144) bf16 row-major
    const float* __restrict__ W,             // (262144, 128) fp32
    float* __restrict__ partials)            // (512, 64*128)
{
    __shared__ unsigned short sW[FCC_CHUNK * WPAD];   // 33,792 B

    int tid  = threadIdx.x;
    int blk  = blockIdx.x;
    int k0   = blk * FCC_KRANGE;
    int lane = tid & 63, wv = tid >> 6;
    int ln   = lane & 15, g = lane >> 4;

    f32x4 acc[8];
    #pragma unroll
    for (int j = 0; j < 8; ++j) acc[j] = (f32x4){0.f,0.f,0.f,0.f};

    int skr = tid >> 5;            // staging row group 0..7
    int sn0 = (tid & 31) * 4;      // staging col

    for (int kc = 0; kc < FCC_KRANGE; kc += FCC_CHUNK) {
        // stage W rows [k0+kc, +128) as bf16 into sW (coalesced)
        #pragma unroll 4
        for (int it = 0; it < 16; ++it) {
            int k = skr + it*8;
            float4 v = *reinterpret_cast<const float4*>(
                W + (size_t)(k0 + kc + k)*128 + sn0);
            us4 pk;
            pk[0] = f2bf(v.x); pk[1] = f2bf(v.y);
            pk[2] = f2bf(v.z); pk[3] = f2bf(v.w);
            *reinterpret_cast<us4*>(&sW[k*WPAD + sn0]) = pk;
        }
        __syncthreads();

        #pragma unroll
        for (int ks = 0; ks < 4; ++ks) {
            const unsigned short* ap = c2bf + (size_t)(16*wv + ln)*FCC_K
                                       + k0 + kc + ks*32 + g*8;
            bf16x8 afrag = *reinterpret_cast<const bf16x8*>(ap);
            int rbase = (ks*32 + g*8) * WPAD;
            #pragma unroll
            for (int j = 0; j < 8; ++j) {
                int col = j*16 + ln;
                bf16x8 bfrag;
                #pragma unroll
                for (int e = 0; e < 8; ++e)
                    bfrag[e] = (short)sW[rbase + e*WPAD + col];
                acc[j] = __builtin_amdgcn_mfma_f32_16x16x32_bf16(afrag, bfrag, acc[j], 0, 0, 0);
            }
        }
        __syncthreads();
    }

    float* p = partials + (size_t)blk * 8192;
    #pragma unroll
    for (int j = 0; j < 8; ++j)
      #pragma unroll
      for (int reg = 0; reg < 4; ++reg) {
          int m = 16*wv + g*4 + reg;
          p[m*128 + j*16 + ln] = acc[j][reg];
      }
}

// ---------------------------------------------------------------------------
// Kernel 4: reduce partials -> cvec = relu(sum + bias).
// ---------------------------------------------------------------------------
__global__ __launch_bounds__(256) void fcc_reduce(
    const float* __restrict__ partials,
    const float* __restrict__ bias,
    float* __restrict__ cvec)
{
    __shared__ float sred[4][64];
    int blk = blockIdx.x;
    int t = threadIdx.x;
    int o = blk*64 + (t & 63);
    int pr = t >> 6;
    float s = 0.f;
    #pragma unroll 4
    for (int p = pr; p < FCC_BLOCKS; p += 4)
        s += partials[(size_t)p*8192 + o];
    sred[pr][t & 63] = s;
    __syncthreads();
    if (t < 64) {
        float v = sred[0][t] + sred[1][t] + sred[2][t] + sred[3][t];
        cvec[o] = fmaxf(v + bias[o & 127], 0.f);
    }
}

// ---------------------------------------------------------------------------
// Kernel 5: head — concat(c,g) -> fc1 relu -> fc2 relu -> fc3 sigmoid
// ---------------------------------------------------------------------------
__global__ __launch_bounds__(128) void head_kernel(
    const float* __restrict__ cvec, const float* __restrict__ g,
    const float* __restrict__ w1, const float* __restrict__ bb1,
    const float* __restrict__ w2, const float* __restrict__ bb2,
    const float* __restrict__ w3, const float* __restrict__ bb3,
    float* __restrict__ out)
{
    __shared__ float sx[256], sh[128], s2[64];
    int b = blockIdx.x, tid = threadIdx.x;
    sx[tid]       = cvec[b*128 + tid];
    sx[128 + tid] = g[b*128 + tid];
    __syncthreads();
    {
        float acc = bb1[tid];
        for (int k = 0; k < 256; ++k) acc += sx[k] * w1[k*128 + tid];
        sh[tid] = fmaxf(acc, 0.f);
    }
    __syncthreads();
    if (tid < 64) {
        float acc = bb2[tid];
        for (int k = 0; k < 128; ++k) acc += sh[k] * w2[k*64 + tid];
        s2[tid] = fmaxf(acc, 0.f);
    }
    __syncthreads();
    if (tid < 2) {
        float acc = bb3[tid];
        for (int k = 0; k < 64; ++k) acc += s2[k] * w3[k*2 + tid];
        out[b*2 + tid] = 1.f / (1.f + __expf(-acc));
    }
}

// ---------------------------------------------------------------------------
extern "C" void kernel_launch(void* const* d_in, const int* in_sizes, int n_in,
                              void* d_out, int out_size, void* d_ws, size_t ws_size,
                              hipStream_t stream)
{
    const float* x1      = (const float*)d_in[0];
    const float* x2      = (const float*)d_in[1];
    const float* gcn1_w  = (const float*)d_in[2];
    const float* gcn1_b  = (const float*)d_in[3];
    const float* gcn2_w  = (const float*)d_in[4];
    const float* gcn2_b  = (const float*)d_in[5];
    const float* fcg_w   = (const float*)d_in[6];
    const float* fcg_b   = (const float*)d_in[7];
    const float* conv1_w = (const float*)d_in[8];
    const float* conv1_b = (const float*)d_in[9];
    const float* conv2_w = (const float*)d_in[10];
    const float* conv2_b = (const float*)d_in[11];
    const float* fcc_w   = (const float*)d_in[12];
    const float* fcc_b   = (const float*)d_in[13];
    const float* fc1_w   = (const float*)d_in[14];
    const float* fc1_b   = (const float*)d_in[15];
    const float* fc2_w   = (const float*)d_in[16];
    const float* fc2_b   = (const float*)d_in[17];
    const float* fc3_w   = (const float*)d_in[18];
    const float* fc3_b   = (const float*)d_in[19];
    float* out = (float*)d_out;

    // workspace layout
    float* ws = (float*)d_ws;
    float* g        = ws;                          // 8,192 f
    unsigned short* c2bf = (unsigned short*)(g + 8192);   // 16,777,216 bf16
    float* partials = (float*)(c2bf + 16777216);   // 512*8192 = 4,194,304 f
    float* cvec     = partials + 4194304;          // 8,192 f
    // total ~50.4 MB

    gcnfcg_kernel<<<64, 128, 0, stream>>>(x1, gcn1_w, gcn1_b, gcn2_w, gcn2_b,
                                          fcg_w, fcg_b, g);
    conv12_kernel<<<2048, 256, 0, stream>>>(x2, conv1_w, conv1_b,
                                            conv2_w, conv2_b, c2bf);
    fcc_mfma<<<FCC_BLOCKS, 256, 0, stream>>>(c2bf, fcc_w, partials);
    fcc_reduce<<<128, 256, 0, stream>>>(partials, fcc_b, cvec);
    head_kernel<<<64, 128, 0, stream>>>(cvec, g, fc1_w, fc1_b, fc2_w, fc2_b,
                                        fc3_w, fc3_b, out);
}